// Round 12
// baseline (708.009 us; speedup 1.0000x reference)
//
#include <hip/hip_runtime.h>
#include <math.h>

#define H    64
#define N    256
#define D    128
#define L    16
#define SEG4   112                 // float4 per 448-col segment
#define F3IN (N * 448)             // 114688 floats per W1 row
#define ROW4 (F3IN / 4)            // 28672 float4 per W1 row
#define CG4   1792                 // float4 per column group (16 segments)

typedef float v4f __attribute__((ext_vector_type(4)));

__device__ __forceinline__ float dot4(float4 a, float4 b) {
    return a.x * b.x + a.y * b.y + a.z * b.z + a.w * b.w;
}
__device__ __forceinline__ float dotv(v4f a, v4f b) {
    return a[0] * b[0] + a[1] * b[1] + a[2] * b[2] + a[3] * b[3];
}

#define NTL(p) __builtin_nontemporal_load(p)
// load one W1 row chunk (7 x v4f) into named regs
#define LOAD_ROW(P0, P1, P2, P3, P4, P5, P6, r)                                \
    { const v4f* _w = wbase + (size_t)(r) * ROW4;                              \
      P0 = NTL(_w); P1 = NTL(_w + 256); P2 = NTL(_w + 512);                    \
      P3 = NTL(_w + 768); P4 = NTL(_w + 1024); P5 = NTL(_w + 1280);            \
      P6 = NTL(_w + 1536); }
#define DOT_BUF(P0, P1, P2, P3, P4, P5, P6)                                    \
    (((dotv(P0, xr[0]) + dotv(P1, xr[1])) + (dotv(P2, xr[2]) + dotv(P3, xr[3])))\
     + ((dotv(P4, xr[4]) + dotv(P5, xr[5])) + dotv(P6, xr[6])))
#define WREDUCE(S, RR)                                                         \
    { float _s = S;                                                            \
      _Pragma("unroll")                                                        \
      for (int _o = 32; _o > 0; _o >>= 1) _s += __shfl_down(_s, _o, 64);       \
      if (lane == 0) red8[RR][wave] = _s; }

// ---------------------------------------------------------------------------
// Single fused kernel. 1024 blocks x 256 threads, __launch_bounds__(256,4)
// => <=128 VGPR, ~21KB LDS => 4 blocks/CU => ALL 1024 blocks co-resident at
// t=0 (deadlock-free spin regardless of dispatch order).
//   block 0:   encoder (emb+GRU+f1W transform+factored softmax; Z_ij =
//              u_i+v_j+const, const cancels) -> ws, __threadfence, flag=1.
//   blocks>0:  issue first 2 W1 rows (14 nt loads, ~57MB chip-wide in
//              flight), THEN park on flag (t0 spin + s_sleep) -> HBM streams
//              during the encoder. After flag: virtual-x, 8 rows pipelined
//              2-deep in named register buffers.
// ---------------------------------------------------------------------------
__global__ __launch_bounds__(256, 4) void k_all(
    const int* __restrict__ token_ids, const float* __restrict__ emb_table,
    const float* __restrict__ Wih, const float* __restrict__ Whh,
    const float* __restrict__ bih, const float* __restrict__ bhh,
    const float* __restrict__ f1W, const float* __restrict__ obs,
    const float* __restrict__ W1,
    float* __restrict__ g_out, float* __restrict__ eus_out,
    float* __restrict__ ev_out, int* __restrict__ flag,
    float* __restrict__ partial)
{
    __shared__ float emb_s[L * H];      // 4KB
    __shared__ float gi_all[L * 192];   // 12KB
    __shared__ float h_s[H];
    __shared__ float gh_s[192];
    __shared__ float wa_s[D];
    __shared__ float wb_s[D];
    __shared__ float u_arr[N];
    __shared__ float v_arr[N];
    __shared__ float wred[4][4];
    __shared__ float red8[8][4];

    const int t = threadIdx.x;
    const int wave = t >> 6, lane = t & 63;
    const int bid = blockIdx.x;

    if (bid == 0) {
        // ------------------- encoder (lean-register) -------------------
        {
            int tok = token_ids[t >> 4];
            ((float4*)emb_s)[t] = ((const float4*)emb_table)[tok * 16 + (t & 15)];
        }
        if (t < H) h_s[t] = 0.0f;

        float bi = 0.0f, bh = 0.0f;
        if (t < 192) { bi = bih[t]; bh = bhh[t]; }

        // f1W column t preloaded early (64 VGPR; consumed after GRU)
        float f1wreg[64];
#pragma unroll
        for (int kk = 0; kk < 64; ++kk) f1wreg[kk] = f1W[kk * 256 + t];

        __syncthreads();

        // hoist input-gate terms: gi_all[tt][k] = bih + Wih[k,:].emb[tt]
        if (t < 192) {
            float gi[L];
#pragma unroll
            for (int tt = 0; tt < L; ++tt) gi[tt] = bi;
            const float4* wi = (const float4*)(Wih + t * H);
#pragma unroll
            for (int c = 0; c < 16; ++c) {
                float4 w = wi[c];
#pragma unroll
                for (int tt = 0; tt < L; ++tt)
                    gi[tt] += dot4(w, ((const float4*)(emb_s + tt * 64))[c]);
            }
#pragma unroll
            for (int tt = 0; tt < L; ++tt) gi_all[tt * 192 + t] = gi[tt];
        }
        __syncthreads();

        // serial GRU; Whh direct reads (L1/L2-resident after step 1)
        for (int tt = 0; tt < L; ++tt) {
            if (t < 192) {
                const float4* wh = (const float4*)(Whh + t * H);
                const float4* hv = (const float4*)h_s;
                float a0 = 0, a1 = 0, a2 = 0, a3 = 0;
#pragma unroll
                for (int c = 0; c < 16; c += 4) {
                    a0 += dot4(wh[c],     hv[c]);
                    a1 += dot4(wh[c + 1], hv[c + 1]);
                    a2 += dot4(wh[c + 2], hv[c + 2]);
                    a3 += dot4(wh[c + 3], hv[c + 3]);
                }
                gh_s[t] = (a0 + a1) + (a2 + a3) + bh;
            }
            __syncthreads();
            if (t < H) {
                float r = 1.0f / (1.0f + expf(-(gi_all[tt * 192 + t] + gh_s[t])));
                float z = 1.0f / (1.0f + expf(-(gi_all[tt * 192 + 64 + t] + gh_s[64 + t])));
                float n = tanhf(gi_all[tt * 192 + 128 + t] + r * gh_s[128 + t]);
                h_s[t] = (1.0f - z) * n + z * h_s[t];
            }
            __syncthreads();
        }

        // wa/wb from preloaded f1W column
        {
            float s = 0.0f;
#pragma unroll
            for (int kk = 0; kk < 64; ++kk) s += f1wreg[kk] * h_s[kk];
            if (t < D) wa_s[t] = s;
            else       wb_s[t - D] = s;
            if (t < H) g_out[t] = h_s[t];
        }
        __syncthreads();

        // u/v cooperative: 32-lane group per row, coalesced
        {
            const float4* obs4 = (const float4*)obs;
            const int grp = t >> 5, cl = t & 31;
            float4 wav = ((const float4*)wa_s)[cl];
            float4 wbv = ((const float4*)wb_s)[cl];
#pragma unroll 4
            for (int it = 0; it < 32; ++it) {
                int row = it * 8 + grp;
                float4 o = obs4[row * 32 + cl];
                float pu = dot4(o, wav);
                float pv = dot4(o, wbv);
#pragma unroll
                for (int off = 16; off > 0; off >>= 1) {
                    pu += __shfl_down(pu, off, 32);
                    pv += __shfl_down(pv, off, 32);
                }
                if (cl == 0) { u_arr[row] = pu; v_arr[row] = pv; }
            }
        }
        __syncthreads();

        const float u = u_arr[t], v = v_arr[t];
        float um = u, vm = v;
#pragma unroll
        for (int off = 32; off > 0; off >>= 1) {
            um = fmaxf(um, __shfl_xor(um, off, 64));
            vm = fmaxf(vm, __shfl_xor(vm, off, 64));
        }
        if (lane == 0) { wred[0][wave] = um; wred[1][wave] = vm; }
        __syncthreads();
        const float mu = fmaxf(fmaxf(wred[0][0], wred[0][1]), fmaxf(wred[0][2], wred[0][3]));
        const float mv = fmaxf(fmaxf(wred[1][0], wred[1][1]), fmaxf(wred[1][2], wred[1][3]));

        const float eui = expf(u - mu), evi = expf(v - mv);
        float us = eui, vs = evi;
#pragma unroll
        for (int off = 32; off > 0; off >>= 1) {
            us += __shfl_xor(us, off, 64);
            vs += __shfl_xor(vs, off, 64);
        }
        if (lane == 0) { wred[2][wave] = us; wred[3][wave] = vs; }
        __syncthreads();
        const float Su = (wred[2][0] + wred[2][1]) + (wred[2][2] + wred[2][3]);
        const float Sv = (wred[3][0] + wred[3][1]) + (wred[3][2] + wred[3][3]);

        eus_out[t] = eui * (1.0f / (Su * Sv));
        ev_out[t]  = evi;
        __syncthreads();                  // all stores issued & drained
        if (t == 0) {
            __threadfence();              // L2 writeback to device scope
            __hip_atomic_store(flag, 1, __ATOMIC_RELEASE, __HIP_MEMORY_SCOPE_AGENT);
        }
    }

    // ------------------- W1 stream (all 1024 blocks) -------------------
    const int cg   = bid & 15;
    const int rgrp = bid >> 4;             // 0..63 -> rows rgrp*8 .. +7
    const v4f* wbase = (const v4f*)W1 + (size_t)(rgrp * 8) * ROW4
                     + (size_t)cg * CG4 + t;

    // prefetch rows 0,1 BEFORE parking (block 0: after enc, no spin)
    v4f A0, A1, A2, A3, A4, A5, A6;
    v4f B0, B1, B2, B3, B4, B5, B6;
    LOAD_ROW(A0, A1, A2, A3, A4, A5, A6, 0);
    LOAD_ROW(B0, B1, B2, B3, B4, B5, B6, 1);
    asm volatile("" ::: "memory");         // pin loads before the spin

    if (bid != 0) {
        if (t == 0) {
            while (__hip_atomic_load(flag, __ATOMIC_ACQUIRE,
                                     __HIP_MEMORY_SCOPE_AGENT) == 0)
                __builtin_amdgcn_s_sleep(2);
        }
        __syncthreads();
    }

    // virtual-x slice for this column group (eus/ev/g from ws, L2)
    v4f xr[7];
    {
        const float4* obs4 = (const float4*)obs;
        const float4* g4   = (const float4*)g_out;
        const float4* ev4  = (const float4*)ev_out;
#pragma unroll
        for (int j = 0; j < 7; ++j) {
            int idx = t + j * 256;           // < 1792
            int s   = idx / SEG4;
            int c   = idx - s * SEG4;
            int seg = cg * 16 + s;
            float4 o;
            if (c < 32)       o = obs4[seg * 32 + c];
            else if (c < 48)  o = g4[c - 32];
            else {
                float4 e = ev4[c - 48];
                float m = eus_out[seg];
                o = make_float4(e.x * m, e.y * m, e.z * m, e.w * m);
            }
            xr[j] = (v4f){o.x, o.y, o.z, o.w};
        }
    }

    // 8 rows, 2-deep register double-buffer pipeline
    float s0, s1, s2, s3, s4, s5, s6, s7;
    s0 = DOT_BUF(A0, A1, A2, A3, A4, A5, A6);
    LOAD_ROW(A0, A1, A2, A3, A4, A5, A6, 2);
    s1 = DOT_BUF(B0, B1, B2, B3, B4, B5, B6);
    LOAD_ROW(B0, B1, B2, B3, B4, B5, B6, 3);
    s2 = DOT_BUF(A0, A1, A2, A3, A4, A5, A6);
    LOAD_ROW(A0, A1, A2, A3, A4, A5, A6, 4);
    s3 = DOT_BUF(B0, B1, B2, B3, B4, B5, B6);
    LOAD_ROW(B0, B1, B2, B3, B4, B5, B6, 5);
    s4 = DOT_BUF(A0, A1, A2, A3, A4, A5, A6);
    LOAD_ROW(A0, A1, A2, A3, A4, A5, A6, 6);
    s5 = DOT_BUF(B0, B1, B2, B3, B4, B5, B6);
    LOAD_ROW(B0, B1, B2, B3, B4, B5, B6, 7);
    s6 = DOT_BUF(A0, A1, A2, A3, A4, A5, A6);
    s7 = DOT_BUF(B0, B1, B2, B3, B4, B5, B6);

    __syncthreads();     // red8 reuse safe (block 0: after enc phases)
    WREDUCE(s0, 0); WREDUCE(s1, 1); WREDUCE(s2, 2); WREDUCE(s3, 3);
    WREDUCE(s4, 4); WREDUCE(s5, 5); WREDUCE(s6, 6); WREDUCE(s7, 7);
    __syncthreads();
    if (t < 8)
        partial[(rgrp * 8 + t) * 16 + cg] =
            red8[t][0] + red8[t][1] + red8[t][2] + red8[t][3];
}

// ---------------------------------------------------------------------------
// Finish: h1 = relu(sum of 16 partials + b1); out = W2 @ h1 + b2. One block.
// ---------------------------------------------------------------------------
__global__ __launch_bounds__(512) void k_finish(
    const float* __restrict__ partial, const float* __restrict__ b1,
    const float* __restrict__ W2, const float* __restrict__ b2,
    float* __restrict__ out)
{
    __shared__ float h1s[512];
    const int r = threadIdx.x;
    {
        const float4* p4 = (const float4*)(partial + r * 16);
        float4 A = p4[0], B = p4[1], C = p4[2], E = p4[3];
        float s = (A.x + A.y + A.z + A.w) + (B.x + B.y + B.z + B.w)
                + (C.x + C.y + C.z + C.w) + (E.x + E.y + E.z + E.w);
        h1s[r] = fmaxf(s + b1[r], 0.0f);
    }
    __syncthreads();

    const int wave = r >> 6, lane = r & 63;
    for (int row = wave; row < 40; row += 8) {
        float s = 0.0f;
#pragma unroll
        for (int c = 0; c < 8; ++c)
            s += W2[row * 512 + lane + c * 64] * h1s[lane + c * 64];
#pragma unroll
        for (int off = 32; off > 0; off >>= 1) s += __shfl_down(s, off, 64);
        if (lane == 0) out[row] = s + b2[row];
    }
}

// ---------------------------------------------------------------------------
extern "C" void kernel_launch(void* const* d_in, const int* in_sizes, int n_in,
                              void* d_out, int out_size, void* d_ws, size_t ws_size,
                              hipStream_t stream)
{
    const float* obs       = (const float*)d_in[0];
    const int*   token_ids = (const int*)  d_in[1];
    const float* emb_table = (const float*)d_in[2];
    const float* Wih       = (const float*)d_in[3];
    const float* Whh       = (const float*)d_in[4];
    const float* bih       = (const float*)d_in[5];
    const float* bhh       = (const float*)d_in[6];
    const float* f1W       = (const float*)d_in[7];
    // d_in[8] = f1_b : cancels in the flat softmax (Z_ij = u_i + v_j + const)
    const float* W1        = (const float*)d_in[9];
    const float* b1        = (const float*)d_in[10];
    const float* W2        = (const float*)d_in[11];
    const float* b2        = (const float*)d_in[12];

    float* ws      = (float*)d_ws;
    float* g       = ws;                     // 64
    float* eus     = ws + 64;                // 256
    float* ev      = ws + 320;               // 256
    int*   flag    = (int*)(ws + 576);       // 1 int (own region)
    float* partial = ws + 640;               // 512*16 = 8192
    float* out     = (float*)d_out;

    hipMemsetAsync(flag, 0, sizeof(int), stream);   // reset handshake flag
    k_all<<<1024, 256, 0, stream>>>(token_ids, emb_table, Wih, Whh, bih, bhh,
                                    f1W, obs, W1, g, eus, ev, flag, partial);
    k_finish<<<1, 512, 0, stream>>>(partial, b1, W2, b2, out);
}